// Round 3
// baseline (142.533 us; speedup 1.0000x reference)
//
#include <hip/hip_runtime.h>

// out[b,c,h,w] = clip(low[b,c,h,w]*cc[b,c], 1e-8, 1) ^ (mask==0 ? g1[b,c] : g2[b,c])
// B=16, C=3, H=W=512. Total = 12,582,912 elems. Pure streaming, 12 B/elem
// -> 151 MB -> ~24 us floor at 6.3 TB/s achievable HBM BW.
//
// R3: same as R2 but with clang native ext_vector_type for the nontemporal
// builtins (HIP_vector_type float4 is a struct -> builtin rejects it).

#define HW_SHIFT 18           // log2(512*512); plane size is a multiple of 8
#define N_TOTAL  12582912     // 16*3*512*512
#define ELEMS_PER_THREAD 8
#define N_THREADS (N_TOTAL / ELEMS_PER_THREAD)   // 1,572,864

typedef float vf4 __attribute__((ext_vector_type(4)));
typedef int   vi4 __attribute__((ext_vector_type(4)));

__global__ __launch_bounds__(256) void gamma_blend_kernel(
    const float* __restrict__ low,
    const float* __restrict__ g1,
    const float* __restrict__ g2,
    const float* __restrict__ cc,
    const int*   __restrict__ mask,
    float*       __restrict__ out)
{
    const int tid = blockIdx.x * blockDim.x + threadIdx.x;
    if (tid >= N_THREADS) return;

    // All 8 consecutive elements live in one (b,c) plane (2^18 % 8 == 0).
    const int bc = (tid * ELEMS_PER_THREAD) >> HW_SHIFT;

    const float c_s = cc[bc];
    const float e1  = g1[bc];
    const float e2  = g2[bc];

    const vf4* lp = reinterpret_cast<const vf4*>(low)  + 2 * tid;
    const vi4* mp = reinterpret_cast<const vi4*>(mask) + 2 * tid;
    vf4*       op = reinterpret_cast<vf4*>(out)        + 2 * tid;

    // Independent loads up front -> 4 outstanding vmem ops per thread.
    const vf4 lv0 = __builtin_nontemporal_load(lp);
    const vf4 lv1 = __builtin_nontemporal_load(lp + 1);
    const vi4 mv0 = __builtin_nontemporal_load(mp);
    const vi4 mv1 = __builtin_nontemporal_load(mp + 1);

    vf4 ov0, ov1;

    #define DO_ELEM(dst, lsrc, msrc)                                        \
        {                                                                   \
            float x = fminf(fmaxf((lsrc) * c_s, 1e-8f), 1.0f);              \
            float g = ((msrc) == 0) ? e1 : e2;                              \
            dst = __builtin_amdgcn_exp2f(g * __builtin_amdgcn_logf(x));     \
        }

    DO_ELEM(ov0.x, lv0.x, mv0.x)
    DO_ELEM(ov0.y, lv0.y, mv0.y)
    DO_ELEM(ov0.z, lv0.z, mv0.z)
    DO_ELEM(ov0.w, lv0.w, mv0.w)
    DO_ELEM(ov1.x, lv1.x, mv1.x)
    DO_ELEM(ov1.y, lv1.y, mv1.y)
    DO_ELEM(ov1.z, lv1.z, mv1.z)
    DO_ELEM(ov1.w, lv1.w, mv1.w)

    #undef DO_ELEM

    __builtin_nontemporal_store(ov0, op);
    __builtin_nontemporal_store(ov1, op + 1);
}

extern "C" void kernel_launch(void* const* d_in, const int* in_sizes, int n_in,
                              void* d_out, int out_size, void* d_ws, size_t ws_size,
                              hipStream_t stream) {
    // setup_inputs order: low_img, g1, g2, c, I_Mask
    const float* low  = (const float*)d_in[0];
    const float* g1   = (const float*)d_in[1];
    const float* g2   = (const float*)d_in[2];
    const float* cc   = (const float*)d_in[3];
    const int*   mask = (const int*)d_in[4];
    float* out = (float*)d_out;

    const int threads = 256;
    const int blocks  = N_THREADS / threads;   // 6144, exact fit
    gamma_blend_kernel<<<blocks, threads, 0, stream>>>(low, g1, g2, cc, mask, out);
}